// Round 7
// baseline (47.388 us; speedup 1.0000x reference)
//
#include <hip/hip_runtime.h>

// SmallTargetAwareLoss: fused weighted-BCE + dice over B=64, P=512*512.
// pred, target: fp32 [64, 1, 512, 512]. Output: 1 fp32 scalar.
// R6: single fused kernel. Cross-block combine via device-scope float atomics
//     (coherent at L3 — no __threadfence / L2 writeback, which cost 3x in R3).
//     Ordering data-atomics -> counter-atomic via inline "s_waitcnt vmcnt(0)".
//     Finalizing (last) block reads accumulators with atomicAdd(p, 0.f) so the
//     reads come from the coherent point, not a stale local L2.
//     __launch_bounds__(256,4): VGPR cap 128 so batched loads can stay live.

#define B_SAMPLES 64
#define P_ELEMS   262144              // 512*512
#define P4        (P_ELEMS / 4)       // 65536 float4 per sample
#define BPS       32                  // blocks per sample
#define NBLK      (B_SAMPLES * BPS)   // 2048 blocks
#define TPB       256
#define CHUNK4    (P4 / BPS)          // 2048 float4 per block
#define ITERS     (CHUNK4 / TPB)      // 8 float4 per thread
#define BATCH     4                   // float4-pairs in flight per batch
#define ACC_STRIDE 32                 // floats per sample slot (own 128B line)

#define LOG2E 1.44269504088896340736f
#define LN2   0.69314718055994530942f

__global__ __launch_bounds__(TPB, 4) void stal_fused(
        const float* __restrict__ pred,
        const float* __restrict__ target,
        float* __restrict__ acc,          // [B_SAMPLES][ACC_STRIDE], zeroed
        unsigned int* __restrict__ counter,
        float* __restrict__ out) {
    const int blk    = blockIdx.x;
    const int sample = blk >> 5;          // / BPS
    const int bin    = blk & (BPS - 1);
    const int tid    = threadIdx.x;

    const float4* p4 = reinterpret_cast<const float4*>(pred)
                       + (size_t)sample * P4 + (size_t)bin * CHUNK4;
    const float4* t4 = reinterpret_cast<const float4*>(target)
                       + (size_t)sample * P4 + (size_t)bin * CHUNK4;

    // s_l2w = sum(log2(1+e^x)*w), s_xt = sum(x*t),
    // s_p = sum(sigmoid), s_pt = sum(sigmoid*t), s_t = sum(t)
    float s_l2w = 0.f, s_xt = 0.f, s_p = 0.f, s_pt = 0.f, s_t = 0.f;

    #pragma unroll
    for (int g = 0; g < ITERS / BATCH; ++g) {
        float4 xv[BATCH], tv[BATCH];
        #pragma unroll
        for (int i = 0; i < BATCH; ++i) {
            xv[i] = p4[tid + (g * BATCH + i) * TPB];
            tv[i] = t4[tid + (g * BATCH + i) * TPB];
        }
        #pragma unroll
        for (int i = 0; i < BATCH; ++i) {
            #pragma unroll
            for (int j = 0; j < 4; ++j) {
                float x = (&xv[i].x)[j];
                float t = (&tv[i].x)[j];
                // |x| <= ~6 (N(0,1) inputs): exp(x) cannot overflow.
                float u  = __builtin_amdgcn_exp2f(x * LOG2E);  // e^x
                float a  = 1.f + u;
                float r  = __builtin_amdgcn_rcpf(a);
                float p  = u * r;                              // sigmoid(x)
                float l2 = __log2f(a);                         // log2(1+e^x)
                float w  = fmaf(10.f, t, 1.f);                 // pos_weight, t in {0,1}
                s_l2w = fmaf(l2, w, s_l2w);
                s_xt  = fmaf(x,  t, s_xt);
                s_p  += p;
                s_pt  = fmaf(p, t, s_pt);
                s_t  += t;
            }
        }
    }

    // sum(bce*w) = ln2*sum(log2(a)*w) - 11*sum(x*t)   (w|t=1 == 11, t in {0,1})
    float s_bce = fmaf(LN2, s_l2w, -11.f * s_xt);

    // wave (64-lane) shuffle reduction
    for (int off = 32; off > 0; off >>= 1) {
        s_bce += __shfl_down(s_bce, off);
        s_pt  += __shfl_down(s_pt,  off);
        s_p   += __shfl_down(s_p,   off);
        s_t   += __shfl_down(s_t,   off);
    }

    __shared__ float red[4][4];
    __shared__ int   is_last;
    const int wave = tid >> 6;
    const int lane = tid & 63;
    if (lane == 0) {
        red[wave][0] = s_bce; red[wave][1] = s_pt;
        red[wave][2] = s_p;   red[wave][3] = s_t;
    }
    __syncthreads();
    if (tid == 0) {
        float a = 0.f, b = 0.f, c = 0.f, d = 0.f;
        for (int w = 0; w < 4; ++w) {
            a += red[w][0]; b += red[w][1]; c += red[w][2]; d += red[w][3];
        }
        float* s = acc + (size_t)sample * ACC_STRIDE;
        atomicAdd(s + 0, a);   // device-scope coherent, no fence needed
        atomicAdd(s + 1, b);
        atomicAdd(s + 2, c);
        atomicAdd(s + 3, d);
        // Order the 4 data atomics before the counter atomic (ack from the
        // coherency point). NOT __threadfence: that emits an L2 writeback.
        asm volatile("s_waitcnt vmcnt(0)" ::: "memory");
        is_last = (atomicAdd(counter, 1u) == NBLK - 1) ? 1 : 0;
    }
    __syncthreads();
    if (!is_last) return;

    // ---- last-arriving block finalizes; all 8192 data atomics are complete ----
    if (tid < B_SAMPLES) {
        float* s = acc + (size_t)tid * ACC_STRIDE;
        // atomic reads: served from the coherent point, never stale local L2
        float S0 = atomicAdd(s + 0, 0.f);
        float S1 = atomicAdd(s + 1, 0.f);
        float S2 = atomicAdd(s + 2, 0.f);
        float S3 = atomicAdd(s + 3, 0.f);

        const float invP = 1.f / (float)P_ELEMS;
        float area  = S3 * invP;
        bool  valid = area < 0.05f;
        float wbce  = S0 * invP;
        float dice  = 1.f - (2.f * S1 + 1e-5f) / (S2 + S3 + 1e-5f);
        float loss  = 0.6f * wbce + 0.4f * dice;

        float v       = valid ? 1.f : 0.f;
        float contrib = valid ? loss : 0.f;
        for (int off = 32; off > 0; off >>= 1) {
            contrib += __shfl_down(contrib, off);
            v       += __shfl_down(v, off);
        }
        if (tid == 0) {
            out[0] = (v > 0.f) ? contrib / fmaxf(v, 1.f) : 0.f;
        }
    }
}

extern "C" void kernel_launch(void* const* d_in, const int* in_sizes, int n_in,
                              void* d_out, int out_size, void* d_ws, size_t ws_size,
                              hipStream_t stream) {
    const float* pred   = (const float*)d_in[0];
    const float* target = (const float*)d_in[1];
    float* out = (float*)d_out;
    float* acc = (float*)d_ws;   // [64][32] floats = 8192 B
    unsigned int* counter = (unsigned int*)((char*)d_ws
                              + B_SAMPLES * ACC_STRIDE * sizeof(float));

    // zero accumulators + counter each launch (graph-legal memset node, 8196 B)
    (void)hipMemsetAsync(d_ws, 0, B_SAMPLES * ACC_STRIDE * sizeof(float)
                                   + sizeof(unsigned int), stream);
    stal_fused<<<NBLK, TPB, 0, stream>>>(pred, target, acc, counter, out);
}

// Round 8
// 27.799 us; speedup vs baseline: 1.7047x; 1.7047x over previous
//
#include <hip/hip_runtime.h>

// SmallTargetAwareLoss: fused weighted-BCE + dice over B=64, P=512*512.
// pred, target: fp32 [64, 1, 512, 512]. Output: 1 fp32 scalar.
// R7: two-kernel structure (fusion is a dead end on gfx950: R3 __threadfence
//     = per-block L2 writeback, 3x regression; R6 contended counter atomic
//     across 2048 co-resident blocks = +20us serialization).
//     Partial: softplus math + 1-deep named-scalar prefetch (modest VGPR ask).
//     Finalize: 256 thr, 4 lanes/sample, pipelined independent loads.

#define B_SAMPLES 64
#define P_ELEMS   262144          // 512*512
#define P4        (P_ELEMS / 4)   // 65536 float4 per sample
#define BPS       32              // blocks per sample
#define NBLK      (B_SAMPLES * BPS)
#define TPB       256
#define CHUNK4    (P4 / BPS)      // 2048 float4 per block
#define ITERS     (CHUNK4 / TPB)  // 8 float4 per thread

#define LOG2E 1.44269504088896340736f
#define LN2   0.69314718055994530942f

__global__ __launch_bounds__(TPB) void stal_partial(
        const float* __restrict__ pred,
        const float* __restrict__ target,
        float* __restrict__ ws) {
    const int blk    = blockIdx.x;
    const int sample = blk >> 5;          // / BPS
    const int bin    = blk & (BPS - 1);
    const int tid    = threadIdx.x;

    const float4* p4 = reinterpret_cast<const float4*>(pred)
                       + (size_t)sample * P4 + (size_t)bin * CHUNK4;
    const float4* t4 = reinterpret_cast<const float4*>(target)
                       + (size_t)sample * P4 + (size_t)bin * CHUNK4;

    // s_l2w = sum(log2(1+e^x)*w), s_xt = sum(x*t),
    // s_p = sum(sigmoid), s_pt = sum(sigmoid*t), s_t = sum(t)
    float s_l2w = 0.f, s_xt = 0.f, s_p = 0.f, s_pt = 0.f, s_t = 0.f;

    // 1-deep software pipeline: load i+1 before computing i.
    float4 xv = p4[tid];
    float4 tv = t4[tid];
    #pragma unroll
    for (int i = 0; i < ITERS; ++i) {
        float4 xv_n, tv_n;
        if (i + 1 < ITERS) {
            xv_n = p4[tid + (i + 1) * TPB];
            tv_n = t4[tid + (i + 1) * TPB];
        }
        #pragma unroll
        for (int j = 0; j < 4; ++j) {
            float x = (&xv.x)[j];
            float t = (&tv.x)[j];
            // |x| <= ~6 (N(0,1) inputs): exp(x) cannot overflow.
            float u  = __builtin_amdgcn_exp2f(x * LOG2E);  // e^x (v_exp_f32)
            float a  = 1.f + u;
            float r  = __builtin_amdgcn_rcpf(a);
            float p  = u * r;                              // sigmoid(x)
            float l2 = __log2f(a);                         // log2(1+e^x)
            float w  = fmaf(10.f, t, 1.f);                 // pos_weight (t in {0,1})
            s_l2w = fmaf(l2, w, s_l2w);
            s_xt  = fmaf(x,  t, s_xt);
            s_p  += p;
            s_pt  = fmaf(p, t, s_pt);
            s_t  += t;
        }
        xv = xv_n;
        tv = tv_n;
    }

    // sum(bce*w) = ln2*sum(log2(a)*w) - 11*sum(x*t)   (w|t=1 == 11, t in {0,1})
    float s_bce = fmaf(LN2, s_l2w, -11.f * s_xt);

    // wave (64-lane) shuffle reduction
    for (int off = 32; off > 0; off >>= 1) {
        s_bce += __shfl_down(s_bce, off);
        s_pt  += __shfl_down(s_pt,  off);
        s_p   += __shfl_down(s_p,   off);
        s_t   += __shfl_down(s_t,   off);
    }

    __shared__ float red[4][4];   // 4 waves x 4 accumulators
    const int wave = tid >> 6;
    const int lane = tid & 63;
    if (lane == 0) {
        red[wave][0] = s_bce; red[wave][1] = s_pt;
        red[wave][2] = s_p;   red[wave][3] = s_t;
    }
    __syncthreads();
    if (tid == 0) {
        float a = 0.f, b = 0.f, c = 0.f, d = 0.f;
        for (int w = 0; w < 4; ++w) {
            a += red[w][0]; b += red[w][1]; c += red[w][2]; d += red[w][3];
        }
        float* o = ws + (size_t)blk * 4;
        o[0] = a; o[1] = b; o[2] = c; o[3] = d;   // every slot rewritten each launch
    }
}

// 256 threads: 4 lanes per sample, each sums 8 of the 32 partials (independent
// addresses -> loads pipeline), then 4-lane shfl_xor combine + per-wave LDS.
__global__ __launch_bounds__(TPB) void stal_finalize(
        const float* __restrict__ ws,
        float* __restrict__ out) {
    const int tid    = threadIdx.x;
    const int sample = tid >> 2;          // 0..63
    const int part   = tid & 3;           // 0..3

    float S0 = 0.f, S1 = 0.f, S2 = 0.f, S3 = 0.f;
    const float4* w4 = reinterpret_cast<const float4*>(ws)
                       + (size_t)sample * BPS + part * (BPS / 4);
    #pragma unroll
    for (int k = 0; k < BPS / 4; ++k) {
        float4 o = w4[k];
        S0 += o.x; S1 += o.y; S2 += o.z; S3 += o.w;
    }
    // combine the 4 parts (lanes sample*4 .. sample*4+3 are wave-adjacent)
    #pragma unroll
    for (int off = 1; off < 4; off <<= 1) {
        S0 += __shfl_xor(S0, off);
        S1 += __shfl_xor(S1, off);
        S2 += __shfl_xor(S2, off);
        S3 += __shfl_xor(S3, off);
    }

    const float invP = 1.f / (float)P_ELEMS;
    float area  = S3 * invP;
    bool  valid = area < 0.05f;
    float wbce  = S0 * invP;
    float dice  = 1.f - (2.f * S1 + 1e-5f) / (S2 + S3 + 1e-5f);
    float loss  = 0.6f * wbce + 0.4f * dice;

    // only part==0 lanes contribute their sample
    float v       = (part == 0 && valid) ? 1.f : 0.f;
    float contrib = (part == 0 && valid) ? loss : 0.f;
    for (int off = 32; off > 0; off >>= 1) {
        contrib += __shfl_down(contrib, off);
        v       += __shfl_down(v, off);
    }

    __shared__ float redc[4], redv[4];
    const int wave = tid >> 6;
    const int lane = tid & 63;
    if (lane == 0) { redc[wave] = contrib; redv[wave] = v; }
    __syncthreads();
    if (tid == 0) {
        float c = redc[0] + redc[1] + redc[2] + redc[3];
        float n = redv[0] + redv[1] + redv[2] + redv[3];
        out[0] = (n > 0.f) ? c / fmaxf(n, 1.f) : 0.f;
    }
}

extern "C" void kernel_launch(void* const* d_in, const int* in_sizes, int n_in,
                              void* d_out, int out_size, void* d_ws, size_t ws_size,
                              hipStream_t stream) {
    const float* pred   = (const float*)d_in[0];
    const float* target = (const float*)d_in[1];
    float* out = (float*)d_out;
    float* ws  = (float*)d_ws;   // 2048*4 floats = 32 KiB, all rewritten per launch

    stal_partial <<<NBLK, TPB, 0, stream>>>(pred, target, ws);
    stal_finalize<<<1, TPB, 0, stream>>>(ws, out);
}